// Round 1
// baseline (8466.448 us; speedup 1.0000x reference)
//
#include <hip/hip_runtime.h>

// RGCN: 2-layer hetero GraphConv, R=4 relations.
// h   = relu( sum_r P_r (x @ W1[r]) + sum_r b1[r] )
// out =       sum_r P_r (h @ W2[r]) + sum_r b2[r]
// where P_r msg folding: coefficient c_e = in_deg_r[dst]^-1/2 * out_deg_r[src]^-1/2
// applied per edge, so all relations accumulate into ONE buffer.

#define RELS 4
#define DIN 256
#define DHID 256
#define DOUT 128

__global__ void deg_kernel(const int* __restrict__ src, const int* __restrict__ dst,
                           float* __restrict__ dsrc, float* __restrict__ ddst,
                           int E, int N) {
    int i = blockIdx.x * blockDim.x + threadIdx.x;
    if (i >= RELS * E) return;
    int r = i / E;
    atomicAdd(dsrc + (size_t)r * N + src[i], 1.0f);
    atomicAdd(ddst + (size_t)r * N + dst[i], 1.0f);
}

__global__ void norm_kernel(float* __restrict__ v, long n) {
    long i = blockIdx.x * (long)blockDim.x + threadIdx.x;
    if (i >= n) return;
    v[i] = rsqrtf(fmaxf(v[i], 1.0f));
}

// Simple f32 tiled GEMM: C[M,N] = A[M,K] @ B[K,N]. Requires BM=64,BN=64,BK=16,
// 256 threads, K % 16 == 0, N % 64 == 0. M guarded.
__global__ __launch_bounds__(256) void gemm_f32(
    const float* __restrict__ A, const float* __restrict__ B,
    float* __restrict__ C, int M, int N, int K) {
    __shared__ float As[16][64 + 1];
    __shared__ float Bs[16][64 + 1];
    int tid = threadIdx.x;
    int tx = tid % 16;          // output col group (4 cols each)
    int ty = tid / 16;          // output row group (4 rows each)
    int brow = blockIdx.x * 64;
    int bcol = blockIdx.y * 64;
    int a_m = tid / 4;          // 0..63
    int a_k = (tid % 4) * 4;    // 0..12
    int b_k = tid / 16;         // 0..15
    int b_n = (tid % 16) * 4;   // 0..60
    float acc[4][4] = {};
    for (int k0 = 0; k0 < K; k0 += 16) {
        float4 av = make_float4(0.f, 0.f, 0.f, 0.f);
        int gm = brow + a_m;
        if (gm < M) av = *(const float4*)(A + (size_t)gm * K + k0 + a_k);
        As[a_k + 0][a_m] = av.x;
        As[a_k + 1][a_m] = av.y;
        As[a_k + 2][a_m] = av.z;
        As[a_k + 3][a_m] = av.w;
        float4 bv = *(const float4*)(B + (size_t)(k0 + b_k) * N + bcol + b_n);
        Bs[b_k][b_n + 0] = bv.x;
        Bs[b_k][b_n + 1] = bv.y;
        Bs[b_k][b_n + 2] = bv.z;
        Bs[b_k][b_n + 3] = bv.w;
        __syncthreads();
#pragma unroll
        for (int kk = 0; kk < 16; ++kk) {
            float ar[4], br[4];
#pragma unroll
            for (int i = 0; i < 4; ++i) ar[i] = As[kk][ty * 4 + i];
#pragma unroll
            for (int j = 0; j < 4; ++j) br[j] = Bs[kk][tx * 4 + j];
#pragma unroll
            for (int i = 0; i < 4; ++i)
#pragma unroll
                for (int j = 0; j < 4; ++j) acc[i][j] += ar[i] * br[j];
        }
        __syncthreads();
    }
#pragma unroll
    for (int i = 0; i < 4; ++i) {
        int gm = brow + ty * 4 + i;
        if (gm < M) {
            float4 v = make_float4(acc[i][0], acc[i][1], acc[i][2], acc[i][3]);
            *(float4*)(C + (size_t)gm * N + bcol + tx * 4) = v;
        }
    }
}

// One edge per wave (64 lanes). D=256: float4 per lane.
__global__ void scatter_d256(const float* __restrict__ xw, const int* __restrict__ src,
                             const int* __restrict__ dst, const float* __restrict__ nsrc,
                             const float* __restrict__ ndst, float* __restrict__ agg, int E) {
    int t = blockIdx.x * blockDim.x + threadIdx.x;
    int e = t >> 6;
    if (e >= E) return;
    int lane = t & 63;
    int s = src[e], d = dst[e];
    float c = nsrc[s] * ndst[d];
    float4 v = ((const float4*)(xw + (size_t)s * 256))[lane];
    float* o = agg + (size_t)d * 256 + lane * 4;
    atomicAdd(o + 0, c * v.x);
    atomicAdd(o + 1, c * v.y);
    atomicAdd(o + 2, c * v.z);
    atomicAdd(o + 3, c * v.w);
}

// D=128: float2 per lane.
__global__ void scatter_d128(const float* __restrict__ hw, const int* __restrict__ src,
                             const int* __restrict__ dst, const float* __restrict__ nsrc,
                             const float* __restrict__ ndst, float* __restrict__ out, int E) {
    int t = blockIdx.x * blockDim.x + threadIdx.x;
    int e = t >> 6;
    if (e >= E) return;
    int lane = t & 63;
    int s = src[e], d = dst[e];
    float c = nsrc[s] * ndst[d];
    float2 v = ((const float2*)(hw + (size_t)s * 128))[lane];
    float* o = out + (size_t)d * 128 + lane * 2;
    atomicAdd(o + 0, c * v.x);
    atomicAdd(o + 1, c * v.y);
}

__global__ void bias_relu_kernel(float* __restrict__ h, const float* __restrict__ b1, long total) {
    long i = blockIdx.x * (long)blockDim.x + threadIdx.x;
    if (i >= total) return;
    int c = (int)(i & (DHID - 1));
    float bs = b1[c] + b1[DHID + c] + b1[2 * DHID + c] + b1[3 * DHID + c];
    h[i] = fmaxf(h[i] + bs, 0.0f);
}

__global__ void out_init_kernel(float* __restrict__ out, const float* __restrict__ b2, long total) {
    long i = blockIdx.x * (long)blockDim.x + threadIdx.x;
    if (i >= total) return;
    int c = (int)(i & (DOUT - 1));
    out[i] = b2[c] + b2[DOUT + c] + b2[2 * DOUT + c] + b2[3 * DOUT + c];
}

extern "C" void kernel_launch(void* const* d_in, const int* in_sizes, int n_in,
                              void* d_out, int out_size, void* d_ws, size_t ws_size,
                              hipStream_t stream) {
    const float* x   = (const float*)d_in[0];
    const int*   src = (const int*)d_in[1];
    const int*   dst = (const int*)d_in[2];
    const float* W1  = (const float*)d_in[3];
    const float* b1  = (const float*)d_in[4];
    const float* W2  = (const float*)d_in[5];
    const float* b2  = (const float*)d_in[6];
    float* out = (float*)d_out;

    const int N = in_sizes[0] / DIN;       // 100000
    const int E = in_sizes[1] / RELS;      // 400000

    // Workspace layout (floats)
    float* ws    = (float*)d_ws;
    float* nsrc  = ws;                               // RELS*N
    float* ndst  = nsrc + (size_t)RELS * N;          // RELS*N
    float* xw    = ndst + (size_t)RELS * N;          // N*DHID
    float* h     = xw   + (size_t)N * DHID;          // N*DHID
    float* hw    = h    + (size_t)N * DHID;          // N*DOUT

    // 1) degrees -> norms
    hipMemsetAsync(nsrc, 0, (size_t)2 * RELS * N * sizeof(float), stream);
    hipMemsetAsync(h, 0, (size_t)N * DHID * sizeof(float), stream);
    {
        int total = RELS * E;
        deg_kernel<<<(total + 255) / 256, 256, 0, stream>>>(src, dst, nsrc, ndst, E, N);
        long ntot = (long)2 * RELS * N;
        norm_kernel<<<(int)((ntot + 255) / 256), 256, 0, stream>>>(nsrc, ntot);
    }

    // 2) layer 1: per relation GEMM + scatter into h
    for (int r = 0; r < RELS; ++r) {
        dim3 grid((N + 63) / 64, DHID / 64);
        gemm_f32<<<grid, 256, 0, stream>>>(x, W1 + (size_t)r * DIN * DHID, xw, N, DHID, DIN);
        long tthr = (long)E * 64;
        scatter_d256<<<(int)((tthr + 255) / 256), 256, 0, stream>>>(
            xw, src + (size_t)r * E, dst + (size_t)r * E,
            nsrc + (size_t)r * N, ndst + (size_t)r * N, h, E);
    }

    // 3) bias + relu
    {
        long total = (long)N * DHID;
        bias_relu_kernel<<<(int)((total + 255) / 256), 256, 0, stream>>>(h, b1, total);
    }

    // 4) layer 2: init out with summed bias, then per relation GEMM + scatter
    {
        long total = (long)N * DOUT;
        out_init_kernel<<<(int)((total + 255) / 256), 256, 0, stream>>>(out, b2, total);
    }
    for (int r = 0; r < RELS; ++r) {
        dim3 grid((N + 63) / 64, DOUT / 64);
        gemm_f32<<<grid, 256, 0, stream>>>(h, W2 + (size_t)r * DHID * DOUT, hw, N, DOUT, DHID);
        long tthr = (long)E * 64;
        scatter_d128<<<(int)((tthr + 255) / 256), 256, 0, stream>>>(
            hw, src + (size_t)r * E, dst + (size_t)r * E,
            nsrc + (size_t)r * N, ndst + (size_t)r * N, out, E);
    }
}

// Round 2
// 2636.713 us; speedup vs baseline: 3.2110x; 3.2110x over previous
//
#include <hip/hip_runtime.h>

// RGCN: 2-layer hetero GraphConv, R=4 relations.
// h   = relu( sum_r P_r (x @ W1[r]) + sum_r b1[r] )
// out =       sum_r P_r (h @ W2[r]) + sum_r b2[r]
// P_r applied per edge with folded coefficient c_e = in_deg_r[dst]^-1/2 * out_deg_r[src]^-1/2.
// R1: atomic scatter replaced by dst-sorted CSR + register gather (no fp atomics).

#define RELS 4
#define DIN 256
#define DHID 256
#define DOUT 128

// ---- CSR build ----------------------------------------------------------

// int histograms of src and dst, all relations in one pass. counts layout [R][N].
__global__ void hist_kernel(const int* __restrict__ src, const int* __restrict__ dst,
                            int* __restrict__ cnt_src, int* __restrict__ cnt_dst,
                            int E, int N) {
    int i = blockIdx.x * blockDim.x + threadIdx.x;
    if (i >= RELS * E) return;
    int r = i / E;
    atomicAdd(cnt_src + (size_t)r * N + src[i], 1);
    atomicAdd(cnt_dst + (size_t)r * N + dst[i], 1);
}

// norms from int degree counts: v = rsqrt(max(cnt,1))
__global__ void norm_kernel(const int* __restrict__ cnt, float* __restrict__ nrm, long n) {
    long i = blockIdx.x * (long)blockDim.x + threadIdx.x;
    if (i >= n) return;
    nrm[i] = rsqrtf(fmaxf((float)cnt[i], 1.0f));
}

// exclusive scan, 3-kernel: per-block scan + block sums, serial scan of sums, add-back.
__global__ void scan_block(const int* __restrict__ counts, int* __restrict__ out,
                           int* __restrict__ blk_sums, int n) {
    __shared__ int sh[256];
    int i = blockIdx.x * 256 + threadIdx.x;
    int v = (i < n) ? counts[i] : 0;
    sh[threadIdx.x] = v;
    __syncthreads();
#pragma unroll
    for (int off = 1; off < 256; off <<= 1) {
        int t = (threadIdx.x >= off) ? sh[threadIdx.x - off] : 0;
        __syncthreads();
        sh[threadIdx.x] += t;
        __syncthreads();
    }
    if (i < n) out[i] = sh[threadIdx.x] - v;           // exclusive
    if (threadIdx.x == 255) blk_sums[blockIdx.x] = sh[255];
}

__global__ void scan_sums(int* __restrict__ blk_sums, int nb) {
    if (threadIdx.x == 0 && blockIdx.x == 0) {
        int acc = 0;
        for (int i = 0; i < nb; ++i) { int v = blk_sums[i]; blk_sums[i] = acc; acc += v; }
    }
}

__global__ void scan_add(int* __restrict__ out, const int* __restrict__ blk_sums, int n, int total) {
    int i = blockIdx.x * 256 + threadIdx.x;
    if (i < n) out[i] += blk_sums[blockIdx.x];
    if (i == n - 1) out[n] = total;                    // row_ptr[N] = E
}

__global__ void cursor_init(const int* __restrict__ row_ptr, int* __restrict__ cursor, int N) {
    int i = blockIdx.x * blockDim.x + threadIdx.x;
    if (i >= RELS * N) return;
    int r = i / N, n = i - r * N;
    cursor[i] = row_ptr[(size_t)r * (N + 1) + n];
}

// place (src, coef) into dst-sorted position
__global__ void fill_kernel(const int* __restrict__ src, const int* __restrict__ dst,
                            const float* __restrict__ nsrc, const float* __restrict__ ndst,
                            int* __restrict__ cursor, int* __restrict__ e_src,
                            float* __restrict__ e_coef, int E, int N) {
    int i = blockIdx.x * blockDim.x + threadIdx.x;
    if (i >= RELS * E) return;
    int r = i / E;
    int s = src[i], d = dst[i];
    int pos = atomicAdd(cursor + (size_t)r * N + d, 1);
    e_src[(size_t)r * E + pos] = s;
    e_coef[(size_t)r * E + pos] = nsrc[(size_t)r * N + s] * ndst[(size_t)r * N + d];
}

// ---- GEMM (f32, 64x64 tile, 4x4 micro) ---------------------------------

__global__ __launch_bounds__(256) void gemm_f32(
    const float* __restrict__ A, const float* __restrict__ B,
    float* __restrict__ C, int M, int N, int K) {
    __shared__ float As[16][64 + 1];
    __shared__ float Bs[16][64 + 1];
    int tid = threadIdx.x;
    int tx = tid % 16;
    int ty = tid / 16;
    int brow = blockIdx.x * 64;
    int bcol = blockIdx.y * 64;
    int a_m = tid / 4;
    int a_k = (tid % 4) * 4;
    int b_k = tid / 16;
    int b_n = (tid % 16) * 4;
    float acc[4][4] = {};
    for (int k0 = 0; k0 < K; k0 += 16) {
        float4 av = make_float4(0.f, 0.f, 0.f, 0.f);
        int gm = brow + a_m;
        if (gm < M) av = *(const float4*)(A + (size_t)gm * K + k0 + a_k);
        As[a_k + 0][a_m] = av.x;
        As[a_k + 1][a_m] = av.y;
        As[a_k + 2][a_m] = av.z;
        As[a_k + 3][a_m] = av.w;
        float4 bv = *(const float4*)(B + (size_t)(k0 + b_k) * N + bcol + b_n);
        Bs[b_k][b_n + 0] = bv.x;
        Bs[b_k][b_n + 1] = bv.y;
        Bs[b_k][b_n + 2] = bv.z;
        Bs[b_k][b_n + 3] = bv.w;
        __syncthreads();
#pragma unroll
        for (int kk = 0; kk < 16; ++kk) {
            float ar[4], br[4];
#pragma unroll
            for (int i = 0; i < 4; ++i) ar[i] = As[kk][ty * 4 + i];
#pragma unroll
            for (int j = 0; j < 4; ++j) br[j] = Bs[kk][tx * 4 + j];
#pragma unroll
            for (int i = 0; i < 4; ++i)
#pragma unroll
                for (int j = 0; j < 4; ++j) acc[i][j] += ar[i] * br[j];
        }
        __syncthreads();
    }
#pragma unroll
    for (int i = 0; i < 4; ++i) {
        int gm = brow + ty * 4 + i;
        if (gm < M) {
            float4 v = make_float4(acc[i][0], acc[i][1], acc[i][2], acc[i][3]);
            *(float4*)(C + (size_t)gm * N + bcol + tx * 4) = v;
        }
    }
}

// ---- CSR gather: one wave per dst node, no atomics ----------------------

template <int D, bool ACC>
__global__ void gather_kernel(const float* __restrict__ feat, const int* __restrict__ row_ptr,
                              const int* __restrict__ e_src, const float* __restrict__ e_coef,
                              float* __restrict__ out, int N) {
    int wid = (int)((blockIdx.x * (long)blockDim.x + threadIdx.x) >> 6);
    if (wid >= N) return;
    int lane = threadIdx.x & 63;
    int beg = row_ptr[wid], end = row_ptr[wid + 1];
    if (D == 256) {
        float4 acc = make_float4(0.f, 0.f, 0.f, 0.f);
        for (int e = beg; e < end; ++e) {
            int s = e_src[e];
            float c = e_coef[e];
            float4 v = ((const float4*)(feat + (size_t)s * 256))[lane];
            acc.x += c * v.x; acc.y += c * v.y; acc.z += c * v.z; acc.w += c * v.w;
        }
        float4* o = (float4*)(out + (size_t)wid * 256) + lane;
        if (ACC) {
            float4 p = *o;
            p.x += acc.x; p.y += acc.y; p.z += acc.z; p.w += acc.w;
            *o = p;
        } else {
            *o = acc;
        }
    } else {  // D == 128
        float2 acc = make_float2(0.f, 0.f);
        for (int e = beg; e < end; ++e) {
            int s = e_src[e];
            float c = e_coef[e];
            float2 v = ((const float2*)(feat + (size_t)s * 128))[lane];
            acc.x += c * v.x; acc.y += c * v.y;
        }
        float2* o = (float2*)(out + (size_t)wid * 128) + lane;
        if (ACC) {
            float2 p = *o;
            p.x += acc.x; p.y += acc.y;
            *o = p;
        } else {
            *o = acc;
        }
    }
}

// ---- epilogues -----------------------------------------------------------

__global__ void bias_relu_kernel(float* __restrict__ h, const float* __restrict__ b1, long total) {
    long i = blockIdx.x * (long)blockDim.x + threadIdx.x;
    if (i >= total) return;
    int c = (int)(i & (DHID - 1));
    float bs = b1[c] + b1[DHID + c] + b1[2 * DHID + c] + b1[3 * DHID + c];
    h[i] = fmaxf(h[i] + bs, 0.0f);
}

__global__ void out_init_kernel(float* __restrict__ out, const float* __restrict__ b2, long total) {
    long i = blockIdx.x * (long)blockDim.x + threadIdx.x;
    if (i >= total) return;
    int c = (int)(i & (DOUT - 1));
    out[i] = b2[c] + b2[DOUT + c] + b2[2 * DOUT + c] + b2[3 * DOUT + c];
}

// ---- launch --------------------------------------------------------------

extern "C" void kernel_launch(void* const* d_in, const int* in_sizes, int n_in,
                              void* d_out, int out_size, void* d_ws, size_t ws_size,
                              hipStream_t stream) {
    const float* x   = (const float*)d_in[0];
    const int*   src = (const int*)d_in[1];
    const int*   dst = (const int*)d_in[2];
    const float* W1  = (const float*)d_in[3];
    const float* b1  = (const float*)d_in[4];
    const float* W2  = (const float*)d_in[5];
    const float* b2  = (const float*)d_in[6];
    float* out = (float*)d_out;

    const int N = in_sizes[0] / DIN;       // 100000
    const int E = in_sizes[1] / RELS;      // 400000

    // Workspace layout
    char* p = (char*)d_ws;
    int*   cnt_src = (int*)p;    p += (size_t)RELS * N * sizeof(int);
    int*   cnt_dst = (int*)p;    p += (size_t)RELS * N * sizeof(int);
    float* nsrc    = (float*)p;  p += (size_t)RELS * N * sizeof(float);
    float* ndst    = (float*)p;  p += (size_t)RELS * N * sizeof(float);
    int*   row_ptr = (int*)p;    p += (size_t)RELS * (N + 1) * sizeof(int);
    int*   cursor  = (int*)p;    p += (size_t)RELS * N * sizeof(int);
    int*   e_src   = (int*)p;    p += (size_t)RELS * E * sizeof(int);
    float* e_coef  = (float*)p;  p += (size_t)RELS * E * sizeof(float);
    int*   blk_sums= (int*)p;    p += 1024 * sizeof(int);
    float* xw      = (float*)p;  p += (size_t)N * DHID * sizeof(float);
    float* h       = (float*)p;  p += (size_t)N * DHID * sizeof(float);
    float* hw      = (float*)p;  p += (size_t)N * DOUT * sizeof(float);

    const int nscan = (N + 255) / 256;     // blocks per relation scan

    // 1) degree histograms (int) -> norms
    hipMemsetAsync(cnt_src, 0, (size_t)2 * RELS * N * sizeof(int), stream);
    {
        int total = RELS * E;
        hist_kernel<<<(total + 255) / 256, 256, 0, stream>>>(src, dst, cnt_src, cnt_dst, E, N);
        long ntot = (long)RELS * N;
        norm_kernel<<<(int)((ntot + 255) / 256), 256, 0, stream>>>(cnt_src, nsrc, ntot);
        norm_kernel<<<(int)((ntot + 255) / 256), 256, 0, stream>>>(cnt_dst, ndst, ntot);
    }

    // 2) CSR by dst, per relation: exclusive scan of cnt_dst -> row_ptr
    for (int r = 0; r < RELS; ++r) {
        const int* c = cnt_dst + (size_t)r * N;
        int* rp = row_ptr + (size_t)r * (N + 1);
        scan_block<<<nscan, 256, 0, stream>>>(c, rp, blk_sums, N);
        scan_sums<<<1, 64, 0, stream>>>(blk_sums, nscan);
        scan_add<<<nscan, 256, 0, stream>>>(rp, blk_sums, N, E);
    }
    {
        long ntot = (long)RELS * N;
        cursor_init<<<(int)((ntot + 255) / 256), 256, 0, stream>>>(row_ptr, cursor, N);
        int total = RELS * E;
        fill_kernel<<<(total + 255) / 256, 256, 0, stream>>>(
            src, dst, nsrc, ndst, cursor, e_src, e_coef, E, N);
    }

    // 3) layer 1: per relation GEMM + CSR gather into h
    for (int r = 0; r < RELS; ++r) {
        dim3 grid((N + 63) / 64, DHID / 64);
        gemm_f32<<<grid, 256, 0, stream>>>(x, W1 + (size_t)r * DIN * DHID, xw, N, DHID, DIN);
        int gblocks = (N + 3) / 4;  // 4 waves per 256-thread block
        const int* rp = row_ptr + (size_t)r * (N + 1);
        const int* es = e_src + (size_t)r * E;
        const float* ec = e_coef + (size_t)r * E;
        if (r == 0)
            gather_kernel<256, false><<<gblocks, 256, 0, stream>>>(xw, rp, es, ec, h, N);
        else
            gather_kernel<256, true><<<gblocks, 256, 0, stream>>>(xw, rp, es, ec, h, N);
    }

    // 4) bias + relu
    {
        long total = (long)N * DHID;
        bias_relu_kernel<<<(int)((total + 255) / 256), 256, 0, stream>>>(h, b1, total);
    }

    // 5) layer 2: init out with summed bias, then per relation GEMM + gather
    {
        long total = (long)N * DOUT;
        out_init_kernel<<<(int)((total + 255) / 256), 256, 0, stream>>>(out, b2, total);
    }
    for (int r = 0; r < RELS; ++r) {
        dim3 grid((N + 63) / 64, DOUT / 64);
        gemm_f32<<<grid, 256, 0, stream>>>(h, W2 + (size_t)r * DHID * DOUT, hw, N, DOUT, DHID);
        int gblocks = (N + 3) / 4;
        const int* rp = row_ptr + (size_t)r * (N + 1);
        const int* es = e_src + (size_t)r * E;
        const float* ec = e_coef + (size_t)r * E;
        gather_kernel<128, true><<<gblocks, 256, 0, stream>>>(hw, rp, es, ec, out, N);
    }
}

// Round 3
// 1411.619 us; speedup vs baseline: 5.9977x; 1.8679x over previous
//
#include <hip/hip_runtime.h>

// RGCN: 2-layer hetero GraphConv, R=4 relations.
// R1: CSR gather (no fp atomics). R2: bf16 MFMA GEMM (16x16x32, 128^2 tile,
// global_load_lds staging, XOR-swizzled LDS), f32 accumulate.

#define RELS 4
#define DIN 256
#define DHID 256
#define DOUT 128

typedef short short8 __attribute__((ext_vector_type(8)));
typedef float f32x4 __attribute__((ext_vector_type(4)));

// ---- CSR build ----------------------------------------------------------

__global__ void hist_kernel(const int* __restrict__ src, const int* __restrict__ dst,
                            int* __restrict__ cnt_src, int* __restrict__ cnt_dst,
                            int E, int N) {
    int i = blockIdx.x * blockDim.x + threadIdx.x;
    if (i >= RELS * E) return;
    int r = i / E;
    atomicAdd(cnt_src + (size_t)r * N + src[i], 1);
    atomicAdd(cnt_dst + (size_t)r * N + dst[i], 1);
}

__global__ void norm_kernel(const int* __restrict__ cnt, float* __restrict__ nrm, long n) {
    long i = blockIdx.x * (long)blockDim.x + threadIdx.x;
    if (i >= n) return;
    nrm[i] = rsqrtf(fmaxf((float)cnt[i], 1.0f));
}

__global__ void scan_block(const int* __restrict__ counts, int* __restrict__ out,
                           int* __restrict__ blk_sums, int n) {
    __shared__ int sh[256];
    int i = blockIdx.x * 256 + threadIdx.x;
    int v = (i < n) ? counts[i] : 0;
    sh[threadIdx.x] = v;
    __syncthreads();
#pragma unroll
    for (int off = 1; off < 256; off <<= 1) {
        int t = (threadIdx.x >= off) ? sh[threadIdx.x - off] : 0;
        __syncthreads();
        sh[threadIdx.x] += t;
        __syncthreads();
    }
    if (i < n) out[i] = sh[threadIdx.x] - v;
    if (threadIdx.x == 255) blk_sums[blockIdx.x] = sh[255];
}

__global__ void scan_sums(int* __restrict__ blk_sums, int nb) {
    if (threadIdx.x == 0 && blockIdx.x == 0) {
        int acc = 0;
        for (int i = 0; i < nb; ++i) { int v = blk_sums[i]; blk_sums[i] = acc; acc += v; }
    }
}

__global__ void scan_add(int* __restrict__ out, const int* __restrict__ blk_sums, int n, int total) {
    int i = blockIdx.x * 256 + threadIdx.x;
    if (i < n) out[i] += blk_sums[blockIdx.x];
    if (i == n - 1) out[n] = total;
}

__global__ void cursor_init(const int* __restrict__ row_ptr, int* __restrict__ cursor, int N) {
    int i = blockIdx.x * blockDim.x + threadIdx.x;
    if (i >= RELS * N) return;
    int r = i / N, n = i - r * N;
    cursor[i] = row_ptr[(size_t)r * (N + 1) + n];
}

__global__ void fill_kernel(const int* __restrict__ src, const int* __restrict__ dst,
                            const float* __restrict__ nsrc, const float* __restrict__ ndst,
                            int* __restrict__ cursor, int* __restrict__ e_src,
                            float* __restrict__ e_coef, int E, int N) {
    int i = blockIdx.x * blockDim.x + threadIdx.x;
    if (i >= RELS * E) return;
    int r = i / E;
    int s = src[i], d = dst[i];
    int pos = atomicAdd(cursor + (size_t)r * N + d, 1);
    e_src[(size_t)r * E + pos] = s;
    e_coef[(size_t)r * E + pos] = nsrc[(size_t)r * N + s] * ndst[(size_t)r * N + d];
}

// ---- dtype conversion ----------------------------------------------------

__device__ __forceinline__ unsigned short f2bf(float f) {
    unsigned int u = __float_as_uint(f);
    u += 0x7FFFu + ((u >> 16) & 1u);   // round-to-nearest-even
    return (unsigned short)(u >> 16);
}

// n8 = total/8; 8 elems per thread
__global__ void f32_to_bf16_kernel(const float* __restrict__ in,
                                   unsigned short* __restrict__ out, long n8) {
    long i = blockIdx.x * (long)blockDim.x + threadIdx.x;
    if (i >= n8) return;
    const float4* ip = (const float4*)(in + i * 8);
    float4 v0 = ip[0], v1 = ip[1];
    ushort4 o0 = make_ushort4(f2bf(v0.x), f2bf(v0.y), f2bf(v0.z), f2bf(v0.w));
    ushort4 o1 = make_ushort4(f2bf(v1.x), f2bf(v1.y), f2bf(v1.z), f2bf(v1.w));
    ushort4* op = (ushort4*)(out + i * 8);
    op[0] = o0; op[1] = o1;
}

// W [R][K][Nout] f32 -> Wt [R][Nout][K] bf16
__global__ void w_transpose_bf16(const float* __restrict__ W, unsigned short* __restrict__ Wt,
                                 int K, int Nout) {
    int i = blockIdx.x * blockDim.x + threadIdx.x;
    int total = RELS * K * Nout;
    if (i >= total) return;
    int r = i / (K * Nout);
    int rem = i - r * (K * Nout);
    int k = rem / Nout, n = rem - k * Nout;
    Wt[(size_t)r * Nout * K + (size_t)n * K + k] = f2bf(W[i]);
}

// ---- bf16 MFMA GEMM: C[M,Nout]f32 = A[M,K]bf16 @ Bt[Nout,K]bf16^T ---------
// BM=BN=128, BK=32, 256 threads (4 waves, 2x2), 4x4 frags of 16x16x32/wave.
// LDS tiles [128][32] bf16, XOR-swizzled at 16B-chunk granularity:
// chunk' = chunk ^ ((chunk>>3)&3)  (involution; applied to global src on
// stage AND to the ds_read address — both-sides rule).

__device__ __forceinline__ void gload_lds16(const void* g, void* l) {
    __builtin_amdgcn_global_load_lds(
        (const __attribute__((address_space(1))) void*)g,
        (__attribute__((address_space(3))) void*)l, 16, 0, 0);
}

__global__ __launch_bounds__(256) void gemm_bf16(
    const unsigned short* __restrict__ A, const unsigned short* __restrict__ Bt,
    float* __restrict__ C, int M, int Nout, int K) {
    __shared__ unsigned short smA[128 * 32];
    __shared__ unsigned short smB[128 * 32];
    const int tid = threadIdx.x;
    const int lane = tid & 63;
    const int wid = tid >> 6;
    const int wr = wid >> 1, wc = wid & 1;
    const int brow = blockIdx.x * 128, bcol = blockIdx.y * 128;

    f32x4 acc[4][4] = {};

    const int s = lane >> 4;      // k-slot for fragment reads
    const int rl = lane & 15;

    for (int k0 = 0; k0 < K; k0 += 32) {
        // stage A,B tiles: 2 rounds x (1KB per wave per buffer)
#pragma unroll
        for (int q = 0; q < 2; ++q) {
            int c = q * 256 + tid;
            int cl = c ^ ((c >> 3) & 3);          // inverse-swizzled source chunk
            int row = cl >> 2, slot = cl & 3;
            int ga = brow + row; ga = ga < M ? ga : M - 1;
            size_t ldsoff = (size_t)(q * 256 + (tid & ~63)) * 16;  // wave-uniform
            gload_lds16(A + (size_t)ga * K + k0 + slot * 8, (char*)smA + ldsoff);
            gload_lds16(Bt + (size_t)(bcol + row) * K + k0 + slot * 8, (char*)smB + ldsoff);
        }
        asm volatile("s_waitcnt vmcnt(0)" ::: "memory");
        __syncthreads();

        short8 a[4], b[4];
#pragma unroll
        for (int i = 0; i < 4; ++i) {
            int r = wr * 64 + i * 16 + rl;
            int ch = r * 4 + (s ^ ((r >> 1) & 3));
            a[i] = *(const short8*)((const char*)smA + ch * 16);
        }
#pragma unroll
        for (int j = 0; j < 4; ++j) {
            int r = wc * 64 + j * 16 + rl;
            int ch = r * 4 + (s ^ ((r >> 1) & 3));
            b[j] = *(const short8*)((const char*)smB + ch * 16);
        }
#pragma unroll
        for (int i = 0; i < 4; ++i)
#pragma unroll
            for (int j = 0; j < 4; ++j)
                acc[i][j] = __builtin_amdgcn_mfma_f32_16x16x32_bf16(a[i], b[j], acc[i][j], 0, 0, 0);
        __syncthreads();
    }

    // C/D layout: col = lane&15, row = (lane>>4)*4 + t
    const int rq = lane >> 4;
#pragma unroll
    for (int i = 0; i < 4; ++i) {
        int rbase = brow + wr * 64 + i * 16 + rq * 4;
#pragma unroll
        for (int j = 0; j < 4; ++j) {
            int col = bcol + wc * 64 + j * 16 + rl;
#pragma unroll
            for (int t = 0; t < 4; ++t) {
                int row = rbase + t;
                if (row < M) C[(size_t)row * Nout + col] = acc[i][j][t];
            }
        }
    }
}

// ---- CSR gather: one wave per dst node ------------------------------------

template <int D, bool ACC>
__global__ void gather_kernel(const float* __restrict__ feat, const int* __restrict__ row_ptr,
                              const int* __restrict__ e_src, const float* __restrict__ e_coef,
                              float* __restrict__ out, int N) {
    int wid = (int)((blockIdx.x * (long)blockDim.x + threadIdx.x) >> 6);
    if (wid >= N) return;
    int lane = threadIdx.x & 63;
    int beg = row_ptr[wid], end = row_ptr[wid + 1];
    if (D == 256) {
        float4 acc = make_float4(0.f, 0.f, 0.f, 0.f);
        for (int e = beg; e < end; ++e) {
            int s = e_src[e];
            float c = e_coef[e];
            float4 v = ((const float4*)(feat + (size_t)s * 256))[lane];
            acc.x += c * v.x; acc.y += c * v.y; acc.z += c * v.z; acc.w += c * v.w;
        }
        float4* o = (float4*)(out + (size_t)wid * 256) + lane;
        if (ACC) {
            float4 p = *o;
            p.x += acc.x; p.y += acc.y; p.z += acc.z; p.w += acc.w;
            *o = p;
        } else {
            *o = acc;
        }
    } else {  // D == 128
        float2 acc = make_float2(0.f, 0.f);
        for (int e = beg; e < end; ++e) {
            int s = e_src[e];
            float c = e_coef[e];
            float2 v = ((const float2*)(feat + (size_t)s * 128))[lane];
            acc.x += c * v.x; acc.y += c * v.y;
        }
        float2* o = (float2*)(out + (size_t)wid * 128) + lane;
        if (ACC) {
            float2 p = *o;
            p.x += acc.x; p.y += acc.y;
            *o = p;
        } else {
            *o = acc;
        }
    }
}

// ---- epilogues -------------------------------------------------------------

// h f32 -> (bias+relu) -> h_bf bf16, 8 elems/thread
__global__ void bias_relu_bf16(const float* __restrict__ h, const float* __restrict__ b1,
                               unsigned short* __restrict__ h_bf, long n8) {
    long i = blockIdx.x * (long)blockDim.x + threadIdx.x;
    if (i >= n8) return;
    long base = i * 8;
    int c0 = (int)(base & (DHID - 1));
    const float4* ip = (const float4*)(h + base);
    float4 v0 = ip[0], v1 = ip[1];
    float vv[8] = {v0.x, v0.y, v0.z, v0.w, v1.x, v1.y, v1.z, v1.w};
    unsigned short o[8];
#pragma unroll
    for (int e = 0; e < 8; ++e) {
        int c = c0 + e;
        float bs = b1[c] + b1[DHID + c] + b1[2 * DHID + c] + b1[3 * DHID + c];
        o[e] = f2bf(fmaxf(vv[e] + bs, 0.0f));
    }
    ushort4* op = (ushort4*)(h_bf + base);
    op[0] = make_ushort4(o[0], o[1], o[2], o[3]);
    op[1] = make_ushort4(o[4], o[5], o[6], o[7]);
}

__global__ void out_init_kernel(float* __restrict__ out, const float* __restrict__ b2, long total) {
    long i = blockIdx.x * (long)blockDim.x + threadIdx.x;
    if (i >= total) return;
    int c = (int)(i & (DOUT - 1));
    out[i] = b2[c] + b2[DOUT + c] + b2[2 * DOUT + c] + b2[3 * DOUT + c];
}

// ---- launch -----------------------------------------------------------------

extern "C" void kernel_launch(void* const* d_in, const int* in_sizes, int n_in,
                              void* d_out, int out_size, void* d_ws, size_t ws_size,
                              hipStream_t stream) {
    const float* x   = (const float*)d_in[0];
    const int*   src = (const int*)d_in[1];
    const int*   dst = (const int*)d_in[2];
    const float* W1  = (const float*)d_in[3];
    const float* b1  = (const float*)d_in[4];
    const float* W2  = (const float*)d_in[5];
    const float* b2  = (const float*)d_in[6];
    float* out = (float*)d_out;

    const int N = in_sizes[0] / DIN;       // 100000
    const int E = in_sizes[1] / RELS;      // 400000

    // Workspace layout
    char* p = (char*)d_ws;
    int*   cnt_src = (int*)p;    p += (size_t)RELS * N * sizeof(int);
    int*   cnt_dst = (int*)p;    p += (size_t)RELS * N * sizeof(int);
    float* nsrc    = (float*)p;  p += (size_t)RELS * N * sizeof(float);
    float* ndst    = (float*)p;  p += (size_t)RELS * N * sizeof(float);
    int*   row_ptr = (int*)p;    p += (size_t)RELS * (N + 1) * sizeof(int);
    int*   cursor  = (int*)p;    p += (size_t)RELS * N * sizeof(int);
    int*   e_src   = (int*)p;    p += (size_t)RELS * E * sizeof(int);
    float* e_coef  = (float*)p;  p += (size_t)RELS * E * sizeof(float);
    int*   blk_sums= (int*)p;    p += 1024 * sizeof(int);
    unsigned short* x_bf  = (unsigned short*)p; p += (size_t)N * DIN * sizeof(short);
    unsigned short* w1t   = (unsigned short*)p; p += (size_t)RELS * DIN * DHID * sizeof(short);
    unsigned short* w2t   = (unsigned short*)p; p += (size_t)RELS * DHID * DOUT * sizeof(short);
    unsigned short* h_bf  = (unsigned short*)p; p += (size_t)N * DHID * sizeof(short);
    float* xw      = (float*)p;  p += (size_t)N * DHID * sizeof(float);  // also hw (layer2)
    float* h       = (float*)p;  p += (size_t)N * DHID * sizeof(float);
    float* hw      = xw;  // alias: xw dead after bias_relu

    const int nscan = (N + 255) / 256;

    // 0) dtype conversions
    {
        long n8 = (long)N * DIN / 8;
        f32_to_bf16_kernel<<<(int)((n8 + 255) / 256), 256, 0, stream>>>(x, x_bf, n8);
        int t1 = RELS * DIN * DHID;
        w_transpose_bf16<<<(t1 + 255) / 256, 256, 0, stream>>>(W1, w1t, DIN, DHID);
        int t2 = RELS * DHID * DOUT;
        w_transpose_bf16<<<(t2 + 255) / 256, 256, 0, stream>>>(W2, w2t, DHID, DOUT);
    }

    // 1) degree histograms -> norms
    hipMemsetAsync(cnt_src, 0, (size_t)2 * RELS * N * sizeof(int), stream);
    {
        int total = RELS * E;
        hist_kernel<<<(total + 255) / 256, 256, 0, stream>>>(src, dst, cnt_src, cnt_dst, E, N);
        long ntot = (long)RELS * N;
        norm_kernel<<<(int)((ntot + 255) / 256), 256, 0, stream>>>(cnt_src, nsrc, ntot);
        norm_kernel<<<(int)((ntot + 255) / 256), 256, 0, stream>>>(cnt_dst, ndst, ntot);
    }

    // 2) CSR by dst per relation
    for (int r = 0; r < RELS; ++r) {
        const int* c = cnt_dst + (size_t)r * N;
        int* rp = row_ptr + (size_t)r * (N + 1);
        scan_block<<<nscan, 256, 0, stream>>>(c, rp, blk_sums, N);
        scan_sums<<<1, 64, 0, stream>>>(blk_sums, nscan);
        scan_add<<<nscan, 256, 0, stream>>>(rp, blk_sums, N, E);
    }
    {
        long ntot = (long)RELS * N;
        cursor_init<<<(int)((ntot + 255) / 256), 256, 0, stream>>>(row_ptr, cursor, N);
        int total = RELS * E;
        fill_kernel<<<(total + 255) / 256, 256, 0, stream>>>(
            src, dst, nsrc, ndst, cursor, e_src, e_coef, E, N);
    }

    // 3) layer 1: per relation MFMA GEMM + CSR gather into h
    const int gx = (N + 127) / 128;
    for (int r = 0; r < RELS; ++r) {
        dim3 grid(gx, DHID / 128);
        gemm_bf16<<<grid, 256, 0, stream>>>(x_bf, w1t + (size_t)r * DIN * DHID, xw, N, DHID, DIN);
        int gblocks = (N + 3) / 4;
        const int* rp = row_ptr + (size_t)r * (N + 1);
        const int* es = e_src + (size_t)r * E;
        const float* ec = e_coef + (size_t)r * E;
        if (r == 0)
            gather_kernel<256, false><<<gblocks, 256, 0, stream>>>(xw, rp, es, ec, h, N);
        else
            gather_kernel<256, true><<<gblocks, 256, 0, stream>>>(xw, rp, es, ec, h, N);
    }

    // 4) bias + relu -> bf16
    {
        long n8 = (long)N * DHID / 8;
        bias_relu_bf16<<<(int)((n8 + 255) / 256), 256, 0, stream>>>(h, b1, h_bf, n8);
    }

    // 5) layer 2
    {
        long total = (long)N * DOUT;
        out_init_kernel<<<(int)((total + 255) / 256), 256, 0, stream>>>(out, b2, total);
    }
    for (int r = 0; r < RELS; ++r) {
        dim3 grid(gx, DOUT / 128);
        gemm_bf16<<<grid, 256, 0, stream>>>(h_bf, w2t + (size_t)r * DHID * DOUT, hw, N, DOUT, DHID);
        int gblocks = (N + 3) / 4;
        const int* rp = row_ptr + (size_t)r * (N + 1);
        const int* es = e_src + (size_t)r * E;
        const float* ec = e_coef + (size_t)r * E;
        gather_kernel<128, true><<<gblocks, 256, 0, stream>>>(hw, rp, es, ec, out, N);
    }
}

// Round 4
// 964.325 us; speedup vs baseline: 8.7797x; 1.4638x over previous
//
#include <hip/hip_runtime.h>

// RGCN: 2-layer hetero GraphConv, R=4 relations.
// R1: CSR gather (no fp atomics). R2: bf16 MFMA GEMM. R3: concat-GEMM across
// relations (epilogue folds src-norm, stores bf16), fused per-node gather over
// all relations (+bias+relu), e_coef eliminated, single global scan.

#define RELS 4
#define DIN 256
#define DHID 256
#define DOUT 128

typedef short short8 __attribute__((ext_vector_type(8)));
typedef float f32x4 __attribute__((ext_vector_type(4)));

// ---- helpers --------------------------------------------------------------

__device__ __forceinline__ unsigned short f2bf(float f) {
    unsigned int u = __float_as_uint(f);
    u += 0x7FFFu + ((u >> 16) & 1u);   // round-to-nearest-even
    return (unsigned short)(u >> 16);
}
__device__ __forceinline__ float bf2f(unsigned short u) {
    return __uint_as_float(((unsigned int)u) << 16);
}

// ---- CSR build --------------------------------------------------------------

__global__ void hist_kernel(const int* __restrict__ src, const int* __restrict__ dst,
                            int* __restrict__ cnt_src, int* __restrict__ cnt_dst,
                            int E, int N) {
    int i = blockIdx.x * blockDim.x + threadIdx.x;
    if (i >= RELS * E) return;
    int r = i / E;
    atomicAdd(cnt_src + (size_t)r * N + src[i], 1);
    atomicAdd(cnt_dst + (size_t)r * N + dst[i], 1);
}

// norms for both cnt_src and cnt_dst in one pass (arrays contiguous)
__global__ void norm_kernel(const int* __restrict__ cnt, float* __restrict__ nrm, long n) {
    long i = blockIdx.x * (long)blockDim.x + threadIdx.x;
    if (i >= n) return;
    nrm[i] = rsqrtf(fmaxf((float)cnt[i], 1.0f));
}

__global__ void scan_block(const int* __restrict__ counts, int* __restrict__ out,
                           int* __restrict__ blk_sums, int n) {
    __shared__ int sh[256];
    int i = blockIdx.x * 256 + threadIdx.x;
    int v = (i < n) ? counts[i] : 0;
    sh[threadIdx.x] = v;
    __syncthreads();
#pragma unroll
    for (int off = 1; off < 256; off <<= 1) {
        int t = (threadIdx.x >= off) ? sh[threadIdx.x - off] : 0;
        __syncthreads();
        sh[threadIdx.x] += t;
        __syncthreads();
    }
    if (i < n) out[i] = sh[threadIdx.x] - v;
    if (threadIdx.x == 255) blk_sums[blockIdx.x] = sh[255];
}

// single-block parallel scan of block sums (chunks of 256 with running carry)
__global__ void scan_sums(int* __restrict__ bs, int nb) {
    __shared__ int sh[256];
    __shared__ int carry;
    if (threadIdx.x == 0) carry = 0;
    __syncthreads();
    for (int base = 0; base < nb; base += 256) {
        int i = base + threadIdx.x;
        int v = (i < nb) ? bs[i] : 0;
        sh[threadIdx.x] = v;
        __syncthreads();
#pragma unroll
        for (int off = 1; off < 256; off <<= 1) {
            int t = (threadIdx.x >= off) ? sh[threadIdx.x - off] : 0;
            __syncthreads();
            sh[threadIdx.x] += t;
            __syncthreads();
        }
        if (i < nb) bs[i] = sh[threadIdx.x] - v + carry;  // exclusive
        int tot = sh[255];
        __syncthreads();
        if (threadIdx.x == 255) carry += tot;
        __syncthreads();
    }
}

__global__ void scan_add(int* __restrict__ out, const int* __restrict__ blk_sums, int n, int total) {
    int i = blockIdx.x * 256 + threadIdx.x;
    if (i < n) out[i] += blk_sums[blockIdx.x];
    if (i == n - 1) out[n] = total;
}

__global__ void cursor_init(const int* __restrict__ row_ptr, int* __restrict__ cursor, int M) {
    int i = blockIdx.x * blockDim.x + threadIdx.x;
    if (i < M) cursor[i] = row_ptr[i];
}

// place src into dst-sorted position (global over all relations)
__global__ void fill_kernel(const int* __restrict__ src, const int* __restrict__ dst,
                            int* __restrict__ cursor, int* __restrict__ e_src, int E, int N) {
    int i = blockIdx.x * blockDim.x + threadIdx.x;
    if (i >= RELS * E) return;
    int r = i / E;
    int pos = atomicAdd(cursor + (size_t)r * N + dst[i], 1);
    e_src[pos] = src[i];
}

// ---- dtype conversion --------------------------------------------------------

__global__ void f32_to_bf16_kernel(const float* __restrict__ in,
                                   unsigned short* __restrict__ out, long n8) {
    long i = blockIdx.x * (long)blockDim.x + threadIdx.x;
    if (i >= n8) return;
    const float4* ip = (const float4*)(in + i * 8);
    float4 v0 = ip[0], v1 = ip[1];
    ushort4 o0 = make_ushort4(f2bf(v0.x), f2bf(v0.y), f2bf(v0.z), f2bf(v0.w));
    ushort4 o1 = make_ushort4(f2bf(v1.x), f2bf(v1.y), f2bf(v1.z), f2bf(v1.w));
    ushort4* op = (ushort4*)(out + i * 8);
    op[0] = o0; op[1] = o1;
}

// W [R][K][Nout] f32 -> Wt [R*Nout][K] bf16
__global__ void w_transpose_bf16(const float* __restrict__ W, unsigned short* __restrict__ Wt,
                                 int K, int Nout) {
    int i = blockIdx.x * blockDim.x + threadIdx.x;
    int total = RELS * K * Nout;
    if (i >= total) return;
    int r = i / (K * Nout);
    int rem = i - r * (K * Nout);
    int k = rem / Nout, n = rem - k * Nout;
    Wt[((size_t)r * Nout + n) * K + k] = f2bf(W[i]);
}

__global__ void bias_sum_kernel(const float* __restrict__ b1, const float* __restrict__ b2,
                                float* __restrict__ b1s, float* __restrict__ b2s) {
    int i = blockIdx.x * blockDim.x + threadIdx.x;
    if (i < DHID) {
        b1s[i] = b1[i] + b1[DHID + i] + b1[2 * DHID + i] + b1[3 * DHID + i];
    } else if (i < DHID + DOUT) {
        int c = i - DHID;
        b2s[c] = b2[c] + b2[DOUT + c] + b2[2 * DOUT + c] + b2[3 * DOUT + c];
    }
}

// ---- bf16 MFMA GEMM: Cbf[M,Nout] = (A[M,K] @ Bt[Nout,K]^T) * nsrc[rel][row] --
// BM=BN=128, BK=32, 256 threads (4 waves 2x2), 4x4 frags of 16x16x32/wave.
// LDS [128][32] bf16 per operand, XOR chunk swizzle (both-sides involution).

__device__ __forceinline__ void gload_lds16(const void* g, void* l) {
    __builtin_amdgcn_global_load_lds(
        (const __attribute__((address_space(1))) void*)g,
        (__attribute__((address_space(3))) void*)l, 16, 0, 0);
}

__global__ __launch_bounds__(256) void gemm_bf16(
    const unsigned short* __restrict__ A, const unsigned short* __restrict__ Bt,
    unsigned short* __restrict__ C, int M, int Nout, int K,
    const float* __restrict__ nsrc, int cols_per_rel, int Nnodes) {
    __shared__ unsigned short smA[128 * 32];
    __shared__ unsigned short smB[128 * 32];
    const int tid = threadIdx.x;
    const int lane = tid & 63;
    const int wid = tid >> 6;
    const int wr = wid >> 1, wc = wid & 1;
    const int brow = blockIdx.x * 128, bcol = blockIdx.y * 128;

    f32x4 acc[4][4] = {};

    const int s = lane >> 4;
    const int rl = lane & 15;

    for (int k0 = 0; k0 < K; k0 += 32) {
#pragma unroll
        for (int q = 0; q < 2; ++q) {
            int c = q * 256 + tid;
            int cl = c ^ ((c >> 3) & 3);
            int row = cl >> 2, slot = cl & 3;
            int ga = brow + row; ga = ga < M ? ga : M - 1;
            size_t ldsoff = (size_t)(q * 256 + (tid & ~63)) * 16;
            gload_lds16(A + (size_t)ga * K + k0 + slot * 8, (char*)smA + ldsoff);
            gload_lds16(Bt + (size_t)(bcol + row) * K + k0 + slot * 8, (char*)smB + ldsoff);
        }
        asm volatile("s_waitcnt vmcnt(0)" ::: "memory");
        __syncthreads();

        short8 a[4], b[4];
#pragma unroll
        for (int i = 0; i < 4; ++i) {
            int r = wr * 64 + i * 16 + rl;
            int ch = r * 4 + (s ^ ((r >> 1) & 3));
            a[i] = *(const short8*)((const char*)smA + ch * 16);
        }
#pragma unroll
        for (int j = 0; j < 4; ++j) {
            int r = wc * 64 + j * 16 + rl;
            int ch = r * 4 + (s ^ ((r >> 1) & 3));
            b[j] = *(const short8*)((const char*)smB + ch * 16);
        }
#pragma unroll
        for (int i = 0; i < 4; ++i)
#pragma unroll
            for (int j = 0; j < 4; ++j)
                acc[i][j] = __builtin_amdgcn_mfma_f32_16x16x32_bf16(a[i], b[j], acc[i][j], 0, 0, 0);
        __syncthreads();
    }

    // epilogue: scale by src-norm of this column block's relation, store bf16.
    const int relid = bcol / cols_per_rel;
    const float* nsr = nsrc + (size_t)relid * Nnodes;
    const int rq = lane >> 4;
#pragma unroll
    for (int i = 0; i < 4; ++i) {
        int rbase = brow + wr * 64 + i * 16 + rq * 4;
        float sc[4];
#pragma unroll
        for (int t = 0; t < 4; ++t) {
            int row = rbase + t;
            sc[t] = (row < M) ? nsr[row] : 0.f;
        }
#pragma unroll
        for (int j = 0; j < 4; ++j) {
            int col = bcol + wc * 64 + j * 16 + rl;
#pragma unroll
            for (int t = 0; t < 4; ++t) {
                int row = rbase + t;
                if (row < M) C[(size_t)row * Nout + col] = f2bf(acc[i][j][t] * sc[t]);
            }
        }
    }
}

// ---- fused gathers: one wave per dst node, all relations -------------------

// layer 1: h_bf[d] = bf16( relu( sum_r ndst_r[d] * sum_e xw4s[src_e, r-block] + b1s ) )
__global__ void gather1_fused(const unsigned short* __restrict__ xw4,
                              const int* __restrict__ rp, const int* __restrict__ e_src,
                              const float* __restrict__ ndst, const float* __restrict__ b1s,
                              unsigned short* __restrict__ h_bf, int N) {
    int wid = (int)((blockIdx.x * (long)blockDim.x + threadIdx.x) >> 6);
    if (wid >= N) return;
    int lane = threadIdx.x & 63;
    float4 hacc = make_float4(0.f, 0.f, 0.f, 0.f);
#pragma unroll
    for (int r = 0; r < RELS; ++r) {
        int beg = rp[r * N + wid], end = rp[r * N + wid + 1];
        float4 acc = make_float4(0.f, 0.f, 0.f, 0.f);
        for (int e = beg; e < end; ++e) {
            int s = e_src[e];
            ushort4 v = *(const ushort4*)(xw4 + (size_t)s * (RELS * DHID) + r * DHID + lane * 4);
            acc.x += bf2f(v.x); acc.y += bf2f(v.y); acc.z += bf2f(v.z); acc.w += bf2f(v.w);
        }
        float nd = ndst[(size_t)r * N + wid];
        hacc.x += nd * acc.x; hacc.y += nd * acc.y;
        hacc.z += nd * acc.z; hacc.w += nd * acc.w;
    }
    float4 b = *(const float4*)(b1s + lane * 4);
    ushort4 o = make_ushort4(f2bf(fmaxf(hacc.x + b.x, 0.f)),
                             f2bf(fmaxf(hacc.y + b.y, 0.f)),
                             f2bf(fmaxf(hacc.z + b.z, 0.f)),
                             f2bf(fmaxf(hacc.w + b.w, 0.f)));
    *(ushort4*)(h_bf + (size_t)wid * DHID + lane * 4) = o;
}

// layer 2: out[d] = sum_r ndst_r[d] * sum_e hw4s[src_e, r-block] + b2s   (f32)
__global__ void gather2_fused(const unsigned short* __restrict__ hw4,
                              const int* __restrict__ rp, const int* __restrict__ e_src,
                              const float* __restrict__ ndst, const float* __restrict__ b2s,
                              float* __restrict__ out, int N) {
    int wid = (int)((blockIdx.x * (long)blockDim.x + threadIdx.x) >> 6);
    if (wid >= N) return;
    int lane = threadIdx.x & 63;
    float2 oacc = make_float2(0.f, 0.f);
#pragma unroll
    for (int r = 0; r < RELS; ++r) {
        int beg = rp[r * N + wid], end = rp[r * N + wid + 1];
        float2 acc = make_float2(0.f, 0.f);
        for (int e = beg; e < end; ++e) {
            int s = e_src[e];
            ushort2 v = *(const ushort2*)(hw4 + (size_t)s * (RELS * DOUT) + r * DOUT + lane * 2);
            acc.x += bf2f(v.x); acc.y += bf2f(v.y);
        }
        float nd = ndst[(size_t)r * N + wid];
        oacc.x += nd * acc.x; oacc.y += nd * acc.y;
    }
    float2 b = *(const float2*)(b2s + lane * 2);
    *(float2*)(out + (size_t)wid * DOUT + lane * 2) = make_float2(oacc.x + b.x, oacc.y + b.y);
}

// ---- launch ------------------------------------------------------------------

extern "C" void kernel_launch(void* const* d_in, const int* in_sizes, int n_in,
                              void* d_out, int out_size, void* d_ws, size_t ws_size,
                              hipStream_t stream) {
    const float* x   = (const float*)d_in[0];
    const int*   src = (const int*)d_in[1];
    const int*   dst = (const int*)d_in[2];
    const float* W1  = (const float*)d_in[3];
    const float* b1  = (const float*)d_in[4];
    const float* W2  = (const float*)d_in[5];
    const float* b2  = (const float*)d_in[6];
    float* out = (float*)d_out;

    const int N = in_sizes[0] / DIN;       // 100000
    const int E = in_sizes[1] / RELS;      // 400000
    const int RN = RELS * N;               // virtual node count

    // Workspace layout
    char* p = (char*)d_ws;
    int*   cnt_src = (int*)p;    p += (size_t)RN * sizeof(int);
    int*   cnt_dst = (int*)p;    p += (size_t)RN * sizeof(int);       // contiguous after cnt_src
    float* nsrc    = (float*)p;  p += (size_t)RN * sizeof(float);
    float* ndst    = (float*)p;  p += (size_t)RN * sizeof(float);     // contiguous after nsrc
    int*   row_ptr = (int*)p;    p += ((size_t)RN + 16) * sizeof(int);
    int*   cursor  = (int*)p;    p += (size_t)RN * sizeof(int);
    int*   e_src   = (int*)p;    p += (size_t)RELS * E * sizeof(int);
    int*   blk_sums= (int*)p;    p += 2048 * sizeof(int);
    float* b1s     = (float*)p;  p += DHID * sizeof(float);
    float* b2s     = (float*)p;  p += DOUT * sizeof(float);
    unsigned short* x_bf = (unsigned short*)p; p += (size_t)N * DIN * sizeof(short);
    unsigned short* w1t  = (unsigned short*)p; p += (size_t)RELS * DIN * DHID * sizeof(short);
    unsigned short* w2t  = (unsigned short*)p; p += (size_t)RELS * DHID * DOUT * sizeof(short);
    unsigned short* h_bf = (unsigned short*)p; p += (size_t)N * DHID * sizeof(short);
    unsigned short* xw4  = (unsigned short*)p; p += (size_t)N * RELS * DHID * sizeof(short);
    unsigned short* hw4  = xw4;   // alias: xw4 dead before layer-2 GEMM writes hw4

    // 0) dtype conversions + bias sums
    {
        long n8 = (long)N * DIN / 8;
        f32_to_bf16_kernel<<<(int)((n8 + 255) / 256), 256, 0, stream>>>(x, x_bf, n8);
        int t1 = RELS * DIN * DHID;
        w_transpose_bf16<<<(t1 + 255) / 256, 256, 0, stream>>>(W1, w1t, DIN, DHID);
        int t2 = RELS * DHID * DOUT;
        w_transpose_bf16<<<(t2 + 255) / 256, 256, 0, stream>>>(W2, w2t, DHID, DOUT);
        bias_sum_kernel<<<2, 256, 0, stream>>>(b1, b2, b1s, b2s);
    }

    // 1) degree histograms -> norms (both in one pass)
    hipMemsetAsync(cnt_src, 0, (size_t)2 * RN * sizeof(int), stream);
    {
        int total = RELS * E;
        hist_kernel<<<(total + 255) / 256, 256, 0, stream>>>(src, dst, cnt_src, cnt_dst, E, N);
        long ntot = (long)2 * RN;
        norm_kernel<<<(int)((ntot + 255) / 256), 256, 0, stream>>>(cnt_src, nsrc, ntot);
    }

    // 2) one global exclusive scan over all RELS*N dst-counts -> row_ptr[RN+1]
    const int nscan = (RN + 255) / 256;
    scan_block<<<nscan, 256, 0, stream>>>(cnt_dst, row_ptr, blk_sums, RN);
    scan_sums<<<1, 256, 0, stream>>>(blk_sums, nscan);
    scan_add<<<nscan, 256, 0, stream>>>(row_ptr, blk_sums, RN, RELS * E);
    cursor_init<<<nscan, 256, 0, stream>>>(row_ptr, cursor, RN);
    {
        int total = RELS * E;
        fill_kernel<<<(total + 255) / 256, 256, 0, stream>>>(src, dst, cursor, e_src, E, N);
    }

    const int gx = (N + 127) / 128;
    const int gblocks = (N + 3) / 4;

    // 3) layer 1: one concat GEMM (Nout=1024) + one fused gather
    {
        dim3 grid(gx, (RELS * DHID) / 128);
        gemm_bf16<<<grid, 256, 0, stream>>>(x_bf, w1t, xw4, N, RELS * DHID, DIN, nsrc, DHID, N);
        gather1_fused<<<gblocks, 256, 0, stream>>>(xw4, row_ptr, e_src, ndst, b1s, h_bf, N);
    }

    // 4) layer 2: one concat GEMM (Nout=512) + one fused gather -> out
    {
        dim3 grid(gx, (RELS * DOUT) / 128);
        gemm_bf16<<<grid, 256, 0, stream>>>(h_bf, w2t, hw4, N, RELS * DOUT, DHID, nsrc, DOUT, N);
        gather2_fused<<<gblocks, 256, 0, stream>>>(hw4, row_ptr, e_src, ndst, b2s, out, N);
    }
}

// Round 5
// 918.153 us; speedup vs baseline: 9.2212x; 1.0503x over previous
//
#include <hip/hip_runtime.h>

// RGCN: 2-layer hetero GraphConv, R=4 relations.
// R1: CSR gather. R2: bf16 MFMA GEMM. R3: concat-GEMM + fused gathers.
// R4: layer 1 aggregate-first — gather x (51MB, L3-resident) into agg4[N][1024],
// then one K=1024 concat GEMM with bias+relu epilogue -> h_bf. Kills the 512MB
// random HBM fetch of the old project-first gather. Layer 2 stays project-first.

#define RELS 4
#define DIN 256
#define DHID 256
#define DOUT 128

typedef short short8 __attribute__((ext_vector_type(8)));
typedef float f32x4 __attribute__((ext_vector_type(4)));

// ---- helpers --------------------------------------------------------------

__device__ __forceinline__ unsigned short f2bf(float f) {
    unsigned int u = __float_as_uint(f);
    u += 0x7FFFu + ((u >> 16) & 1u);   // round-to-nearest-even
    return (unsigned short)(u >> 16);
}
__device__ __forceinline__ float bf2f(unsigned short u) {
    return __uint_as_float(((unsigned int)u) << 16);
}

// ---- CSR build --------------------------------------------------------------

__global__ void hist_kernel(const int* __restrict__ src, const int* __restrict__ dst,
                            int* __restrict__ cnt_src, int* __restrict__ cnt_dst,
                            int E, int N) {
    int i = blockIdx.x * blockDim.x + threadIdx.x;
    if (i >= RELS * E) return;
    int r = i / E;
    atomicAdd(cnt_src + (size_t)r * N + src[i], 1);
    atomicAdd(cnt_dst + (size_t)r * N + dst[i], 1);
}

__global__ void norm_kernel(const int* __restrict__ cnt, float* __restrict__ nrm, long n) {
    long i = blockIdx.x * (long)blockDim.x + threadIdx.x;
    if (i >= n) return;
    nrm[i] = rsqrtf(fmaxf((float)cnt[i], 1.0f));
}

__global__ void scan_block(const int* __restrict__ counts, int* __restrict__ out,
                           int* __restrict__ blk_sums, int n) {
    __shared__ int sh[256];
    int i = blockIdx.x * 256 + threadIdx.x;
    int v = (i < n) ? counts[i] : 0;
    sh[threadIdx.x] = v;
    __syncthreads();
#pragma unroll
    for (int off = 1; off < 256; off <<= 1) {
        int t = (threadIdx.x >= off) ? sh[threadIdx.x - off] : 0;
        __syncthreads();
        sh[threadIdx.x] += t;
        __syncthreads();
    }
    if (i < n) out[i] = sh[threadIdx.x] - v;
    if (threadIdx.x == 255) blk_sums[blockIdx.x] = sh[255];
}

__global__ void scan_sums(int* __restrict__ bs, int nb) {
    __shared__ int sh[256];
    __shared__ int carry;
    if (threadIdx.x == 0) carry = 0;
    __syncthreads();
    for (int base = 0; base < nb; base += 256) {
        int i = base + threadIdx.x;
        int v = (i < nb) ? bs[i] : 0;
        sh[threadIdx.x] = v;
        __syncthreads();
#pragma unroll
        for (int off = 1; off < 256; off <<= 1) {
            int t = (threadIdx.x >= off) ? sh[threadIdx.x - off] : 0;
            __syncthreads();
            sh[threadIdx.x] += t;
            __syncthreads();
        }
        if (i < nb) bs[i] = sh[threadIdx.x] - v + carry;  // exclusive
        int tot = sh[255];
        __syncthreads();
        if (threadIdx.x == 255) carry += tot;
        __syncthreads();
    }
}

__global__ void scan_add(int* __restrict__ out, const int* __restrict__ blk_sums, int n, int total) {
    int i = blockIdx.x * 256 + threadIdx.x;
    if (i < n) out[i] += blk_sums[blockIdx.x];
    if (i == n - 1) out[n] = total;
}

__global__ void cursor_init(const int* __restrict__ row_ptr, int* __restrict__ cursor, int M) {
    int i = blockIdx.x * blockDim.x + threadIdx.x;
    if (i < M) cursor[i] = row_ptr[i];
}

// place (src, src-norm) into dst-sorted position
__global__ void fill_kernel(const int* __restrict__ src, const int* __restrict__ dst,
                            const float* __restrict__ nsrc,
                            int* __restrict__ cursor, int* __restrict__ e_src,
                            float* __restrict__ e_ns, int E, int N) {
    int i = blockIdx.x * blockDim.x + threadIdx.x;
    if (i >= RELS * E) return;
    int r = i / E;
    int s = src[i];
    int pos = atomicAdd(cursor + (size_t)r * N + dst[i], 1);
    e_src[pos] = s;
    e_ns[pos] = nsrc[(size_t)r * N + s];
}

// ---- dtype conversion --------------------------------------------------------

__global__ void f32_to_bf16_kernel(const float* __restrict__ in,
                                   unsigned short* __restrict__ out, long n8) {
    long i = blockIdx.x * (long)blockDim.x + threadIdx.x;
    if (i >= n8) return;
    const float4* ip = (const float4*)(in + i * 8);
    float4 v0 = ip[0], v1 = ip[1];
    ushort4 o0 = make_ushort4(f2bf(v0.x), f2bf(v0.y), f2bf(v0.z), f2bf(v0.w));
    ushort4 o1 = make_ushort4(f2bf(v1.x), f2bf(v1.y), f2bf(v1.z), f2bf(v1.w));
    ushort4* op = (ushort4*)(out + i * 8);
    op[0] = o0; op[1] = o1;
}

// W1 [R][K][Nout] f32 -> Wt [Nout][R*K] bf16  (K-concat layout for agg-first)
__global__ void w1_transpose_cat(const float* __restrict__ W, unsigned short* __restrict__ Wt,
                                 int K, int Nout) {
    int i = blockIdx.x * blockDim.x + threadIdx.x;
    int total = RELS * K * Nout;
    if (i >= total) return;
    int r = i / (K * Nout);
    int rem = i - r * (K * Nout);
    int k = rem / Nout, n = rem - k * Nout;
    Wt[(size_t)n * (RELS * K) + r * K + k] = f2bf(W[i]);
}

// W2 [R][K][Nout] f32 -> Wt [R*Nout][K] bf16  (N-concat layout for project-first)
__global__ void w2_transpose_cat(const float* __restrict__ W, unsigned short* __restrict__ Wt,
                                 int K, int Nout) {
    int i = blockIdx.x * blockDim.x + threadIdx.x;
    int total = RELS * K * Nout;
    if (i >= total) return;
    int r = i / (K * Nout);
    int rem = i - r * (K * Nout);
    int k = rem / Nout, n = rem - k * Nout;
    Wt[((size_t)r * Nout + n) * K + k] = f2bf(W[i]);
}

__global__ void bias_sum_kernel(const float* __restrict__ b1, const float* __restrict__ b2,
                                float* __restrict__ b1s, float* __restrict__ b2s) {
    int i = blockIdx.x * blockDim.x + threadIdx.x;
    if (i < DHID) {
        b1s[i] = b1[i] + b1[DHID + i] + b1[2 * DHID + i] + b1[3 * DHID + i];
    } else if (i < DHID + DOUT) {
        int c = i - DHID;
        b2s[c] = b2[c] + b2[DOUT + c] + b2[2 * DOUT + c] + b2[3 * DOUT + c];
    }
}

// ---- bf16 MFMA GEMM ---------------------------------------------------------
// BM=BN=128, BK=32, 256 threads (4 waves 2x2), 4x4 frags of 16x16x32/wave.
// LDS [128][32] bf16 per operand, XOR chunk swizzle (both-sides involution).
// MODE 0: C = bf16( acc * nsrc[rel][row] )          (layer-2 project-first)
// MODE 1: C = bf16( relu(acc + bias[col]) )         (layer-1 agg-first)

__device__ __forceinline__ void gload_lds16(const void* g, void* l) {
    __builtin_amdgcn_global_load_lds(
        (const __attribute__((address_space(1))) void*)g,
        (__attribute__((address_space(3))) void*)l, 16, 0, 0);
}

template <int MODE>
__global__ __launch_bounds__(256) void gemm_bf16(
    const unsigned short* __restrict__ A, const unsigned short* __restrict__ Bt,
    unsigned short* __restrict__ C, int M, int Nout, int K,
    const float* __restrict__ scale_or_bias, int cols_per_rel, int Nnodes) {
    __shared__ unsigned short smA[128 * 32];
    __shared__ unsigned short smB[128 * 32];
    const int tid = threadIdx.x;
    const int lane = tid & 63;
    const int wid = tid >> 6;
    const int wr = wid >> 1, wc = wid & 1;
    const int brow = blockIdx.x * 128, bcol = blockIdx.y * 128;

    f32x4 acc[4][4] = {};

    const int s = lane >> 4;
    const int rl = lane & 15;

    for (int k0 = 0; k0 < K; k0 += 32) {
#pragma unroll
        for (int q = 0; q < 2; ++q) {
            int c = q * 256 + tid;
            int cl = c ^ ((c >> 3) & 3);
            int row = cl >> 2, slot = cl & 3;
            int ga = brow + row; ga = ga < M ? ga : M - 1;
            size_t ldsoff = (size_t)(q * 256 + (tid & ~63)) * 16;
            gload_lds16(A + (size_t)ga * K + k0 + slot * 8, (char*)smA + ldsoff);
            gload_lds16(Bt + (size_t)(bcol + row) * K + k0 + slot * 8, (char*)smB + ldsoff);
        }
        asm volatile("s_waitcnt vmcnt(0)" ::: "memory");
        __syncthreads();

        short8 a[4], b[4];
#pragma unroll
        for (int i = 0; i < 4; ++i) {
            int r = wr * 64 + i * 16 + rl;
            int ch = r * 4 + (s ^ ((r >> 1) & 3));
            a[i] = *(const short8*)((const char*)smA + ch * 16);
        }
#pragma unroll
        for (int j = 0; j < 4; ++j) {
            int r = wc * 64 + j * 16 + rl;
            int ch = r * 4 + (s ^ ((r >> 1) & 3));
            b[j] = *(const short8*)((const char*)smB + ch * 16);
        }
#pragma unroll
        for (int i = 0; i < 4; ++i)
#pragma unroll
            for (int j = 0; j < 4; ++j)
                acc[i][j] = __builtin_amdgcn_mfma_f32_16x16x32_bf16(a[i], b[j], acc[i][j], 0, 0, 0);
        __syncthreads();
    }

    const int rq = lane >> 4;
    if (MODE == 0) {
        const int relid = bcol / cols_per_rel;
        const float* nsr = scale_or_bias + (size_t)relid * Nnodes;
#pragma unroll
        for (int i = 0; i < 4; ++i) {
            int rbase = brow + wr * 64 + i * 16 + rq * 4;
            float sc[4];
#pragma unroll
            for (int t = 0; t < 4; ++t) {
                int row = rbase + t;
                sc[t] = (row < M) ? nsr[row] : 0.f;
            }
#pragma unroll
            for (int j = 0; j < 4; ++j) {
                int col = bcol + wc * 64 + j * 16 + rl;
#pragma unroll
                for (int t = 0; t < 4; ++t) {
                    int row = rbase + t;
                    if (row < M) C[(size_t)row * Nout + col] = f2bf(acc[i][j][t] * sc[t]);
                }
            }
        }
    } else {
#pragma unroll
        for (int i = 0; i < 4; ++i) {
            int rbase = brow + wr * 64 + i * 16 + rq * 4;
#pragma unroll
            for (int j = 0; j < 4; ++j) {
                int col = bcol + wc * 64 + j * 16 + rl;
                float bb = scale_or_bias[col];
#pragma unroll
                for (int t = 0; t < 4; ++t) {
                    int row = rbase + t;
                    if (row < M) C[(size_t)row * Nout + col] = f2bf(fmaxf(acc[i][j][t] + bb, 0.f));
                }
            }
        }
    }
}

// ---- gathers ---------------------------------------------------------------

// layer 1 aggregate-first: one wave per (node, relation).
// agg4[d][r*256 + c] = ndst_r[d] * sum_e nsrc_r[s_e] * x[s_e][c]
__global__ void gather1_agg(const unsigned short* __restrict__ x_bf,
                            const int* __restrict__ rp, const int* __restrict__ e_src,
                            const float* __restrict__ e_ns, const float* __restrict__ ndst,
                            unsigned short* __restrict__ agg4, int N) {
    long w = (blockIdx.x * (long)blockDim.x + threadIdx.x) >> 6;
    int d = (int)(w >> 2);
    if (d >= N) return;
    int r = (int)(w & 3);
    int lane = threadIdx.x & 63;
    int beg = rp[(size_t)r * N + d], end = rp[(size_t)r * N + d + 1];
    float4 acc = make_float4(0.f, 0.f, 0.f, 0.f);
    for (int e = beg; e < end; ++e) {
        int s = e_src[e];
        float ns = e_ns[e];
        ushort4 v = *(const ushort4*)(x_bf + (size_t)s * DIN + lane * 4);
        acc.x += ns * bf2f(v.x); acc.y += ns * bf2f(v.y);
        acc.z += ns * bf2f(v.z); acc.w += ns * bf2f(v.w);
    }
    float nd = ndst[(size_t)r * N + d];
    ushort4 o = make_ushort4(f2bf(nd * acc.x), f2bf(nd * acc.y),
                             f2bf(nd * acc.z), f2bf(nd * acc.w));
    *(ushort4*)(agg4 + (size_t)d * (RELS * DIN) + r * DIN + lane * 4) = o;
}

// layer 2 project-first: one wave per dst node, all relations; out f32 + bias.
__global__ void gather2_fused(const unsigned short* __restrict__ hw4,
                              const int* __restrict__ rp, const int* __restrict__ e_src,
                              const float* __restrict__ ndst, const float* __restrict__ b2s,
                              float* __restrict__ out, int N) {
    int wid = (int)((blockIdx.x * (long)blockDim.x + threadIdx.x) >> 6);
    if (wid >= N) return;
    int lane = threadIdx.x & 63;
    float2 oacc = make_float2(0.f, 0.f);
#pragma unroll
    for (int r = 0; r < RELS; ++r) {
        int beg = rp[(size_t)r * N + wid], end = rp[(size_t)r * N + wid + 1];
        float2 acc = make_float2(0.f, 0.f);
        for (int e = beg; e < end; ++e) {
            int s = e_src[e];
            ushort2 v = *(const ushort2*)(hw4 + (size_t)s * (RELS * DOUT) + r * DOUT + lane * 2);
            acc.x += bf2f(v.x); acc.y += bf2f(v.y);
        }
        float nd = ndst[(size_t)r * N + wid];
        oacc.x += nd * acc.x; oacc.y += nd * acc.y;
    }
    float2 b = *(const float2*)(b2s + lane * 2);
    *(float2*)(out + (size_t)wid * DOUT + lane * 2) = make_float2(oacc.x + b.x, oacc.y + b.y);
}

// ---- launch ------------------------------------------------------------------

extern "C" void kernel_launch(void* const* d_in, const int* in_sizes, int n_in,
                              void* d_out, int out_size, void* d_ws, size_t ws_size,
                              hipStream_t stream) {
    const float* x   = (const float*)d_in[0];
    const int*   src = (const int*)d_in[1];
    const int*   dst = (const int*)d_in[2];
    const float* W1  = (const float*)d_in[3];
    const float* b1  = (const float*)d_in[4];
    const float* W2  = (const float*)d_in[5];
    const float* b2  = (const float*)d_in[6];
    float* out = (float*)d_out;

    const int N = in_sizes[0] / DIN;       // 100000
    const int E = in_sizes[1] / RELS;      // 400000
    const int RN = RELS * N;

    // Workspace layout
    char* p = (char*)d_ws;
    int*   cnt_src = (int*)p;    p += (size_t)RN * sizeof(int);
    int*   cnt_dst = (int*)p;    p += (size_t)RN * sizeof(int);       // contiguous after cnt_src
    float* nsrc    = (float*)p;  p += (size_t)RN * sizeof(float);
    float* ndst    = (float*)p;  p += (size_t)RN * sizeof(float);     // contiguous after nsrc
    int*   row_ptr = (int*)p;    p += ((size_t)RN + 16) * sizeof(int);
    int*   cursor  = (int*)p;    p += (size_t)RN * sizeof(int);
    int*   e_src   = (int*)p;    p += (size_t)RELS * E * sizeof(int);
    float* e_ns    = (float*)p;  p += (size_t)RELS * E * sizeof(float);
    int*   blk_sums= (int*)p;    p += 2048 * sizeof(int);
    float* b1s     = (float*)p;  p += DHID * sizeof(float);
    float* b2s     = (float*)p;  p += DOUT * sizeof(float);
    unsigned short* x_bf = (unsigned short*)p; p += (size_t)N * DIN * sizeof(short);
    unsigned short* w1t  = (unsigned short*)p; p += (size_t)RELS * DIN * DHID * sizeof(short);
    unsigned short* w2t  = (unsigned short*)p; p += (size_t)RELS * DHID * DOUT * sizeof(short);
    unsigned short* h_bf = (unsigned short*)p; p += (size_t)N * DHID * sizeof(short);
    unsigned short* agg4 = (unsigned short*)p; p += (size_t)N * RELS * DIN * sizeof(short);
    unsigned short* hw4  = agg4;   // alias: agg4 dead after gemm1

    // 0) dtype conversions + bias sums
    {
        long n8 = (long)N * DIN / 8;
        f32_to_bf16_kernel<<<(int)((n8 + 255) / 256), 256, 0, stream>>>(x, x_bf, n8);
        int t1 = RELS * DIN * DHID;
        w1_transpose_cat<<<(t1 + 255) / 256, 256, 0, stream>>>(W1, w1t, DIN, DHID);
        int t2 = RELS * DHID * DOUT;
        w2_transpose_cat<<<(t2 + 255) / 256, 256, 0, stream>>>(W2, w2t, DHID, DOUT);
        bias_sum_kernel<<<2, 256, 0, stream>>>(b1, b2, b1s, b2s);
    }

    // 1) degree histograms -> norms (both tables in one pass)
    hipMemsetAsync(cnt_src, 0, (size_t)2 * RN * sizeof(int), stream);
    {
        int total = RELS * E;
        hist_kernel<<<(total + 255) / 256, 256, 0, stream>>>(src, dst, cnt_src, cnt_dst, E, N);
        long ntot = (long)2 * RN;
        norm_kernel<<<(int)((ntot + 255) / 256), 256, 0, stream>>>(cnt_src, nsrc, ntot);
    }

    // 2) one global exclusive scan over all RELS*N dst-counts -> row_ptr[RN+1]
    const int nscan = (RN + 255) / 256;
    scan_block<<<nscan, 256, 0, stream>>>(cnt_dst, row_ptr, blk_sums, RN);
    scan_sums<<<1, 256, 0, stream>>>(blk_sums, nscan);
    scan_add<<<nscan, 256, 0, stream>>>(row_ptr, blk_sums, RN, RELS * E);
    cursor_init<<<nscan, 256, 0, stream>>>(row_ptr, cursor, RN);
    {
        int total = RELS * E;
        fill_kernel<<<(total + 255) / 256, 256, 0, stream>>>(
            src, dst, nsrc, cursor, e_src, e_ns, E, N);
    }

    const int gx = (N + 127) / 128;

    // 3) layer 1 aggregate-first: gather x -> agg4 [N][1024], then concat GEMM
    //    [N,1024]@[1024,256] with bias+relu epilogue -> h_bf
    {
        long waves = (long)RELS * N;
        int blocks = (int)((waves + 3) / 4);
        gather1_agg<<<blocks, 256, 0, stream>>>(x_bf, row_ptr, e_src, e_ns, ndst, agg4, N);
        dim3 grid(gx, DHID / 128);
        gemm_bf16<1><<<grid, 256, 0, stream>>>(agg4, w1t, h_bf, N, DHID, RELS * DIN, b1s, 0, N);
    }

    // 4) layer 2 project-first: concat GEMM (Nout=512, nsrc epilogue) + gather
    {
        dim3 grid(gx, (RELS * DOUT) / 128);
        gemm_bf16<0><<<grid, 256, 0, stream>>>(h_bf, w2t, hw4, N, RELS * DOUT, DHID, nsrc, DOUT, N);
        int gblocks = (N + 3) / 4;
        gather2_fused<<<gblocks, 256, 0, stream>>>(hw4, row_ptr, e_src, ndst, b2s, out, N);
    }
}